// Round 5
// baseline (197.762 us; speedup 1.0000x reference)
//
#include <hip/hip_runtime.h>
#include <hip/hip_bf16.h>

// MHA forward. Inputs fp32, output fp32, compute bf16 MFMA w/ fp32 accum.
// B=8, N=1024, DIM=768, NH=12, HD=64, M=8192.
// R16 == R15 resubmit (R15 bench was an infra failure: "container failed
// twice", no measurement). Cleaned a dead duplicate 'which' computation.
// R15: fix R14's V-write amplification (WRITE_SIZE 41->54.5MB, qkv 48->55us
// from 8B scattered stores). V blocks (blockIdx.y>=12, block-uniform) now
// bounce the wave's 64x64 acc tile through its PRIVATE 2048-elem LDS region
// (As/Bs dead after K-loop; one barrier) laid out [d=fr][n] stride 72
// (16B-aligned reads), then store d-rows as 16B x 8-adjacent-lane = 128B
// contiguous segments. Wave-local => no extra cross-wave sync beyond the
// one post-loop barrier.
// R14 carried: vtrans kernel deleted (V transposed in qkv epilogue); attn
// double-buffered K/V reusing dead Q LDS region, 1 barrier/KV-tile, 2
// prefetch reg sets (T14), setprio around MFMA (T5).
// R11 carried: GEMM BK=32 128^2 2-phase (R13 proved T2/BK=64 regress here),
// 512-thread attn, bare v_exp_f32, S^T operand swap + sigma permutation,
// XCD swizzle bh=bx%96, deferred l-reduction.
// WS high-water 55,050,240 B (proven available).

typedef __bf16 bf16x8 __attribute__((ext_vector_type(8)));
typedef float f32x4 __attribute__((ext_vector_type(4)));

#define MFMA16(a, b, c) __builtin_amdgcn_mfma_f32_16x16x32_bf16(a, b, c, 0, 0, 0)

#if defined(__has_builtin) && __has_builtin(__builtin_amdgcn_exp2f)
#define EXP2(x) __builtin_amdgcn_exp2f(x)
#else
#define EXP2(x) exp2f(x)
#endif

__device__ inline __bf16 to_bf16(float f) {
  __hip_bfloat16 h = __float2bfloat16(f);
  return *reinterpret_cast<__bf16*>(&h);
}

// Direct global->LDS DMA, 16B per lane. LDS dest is wave-uniform base + lane*16.
__device__ __forceinline__ void gload16(const void* g, void* l) {
  __builtin_amdgcn_global_load_lds(
      (const __attribute__((address_space(1))) unsigned int*)(unsigned long long)g,
      (__attribute__((address_space(3))) unsigned int*)(unsigned long long)l,
      16, 0, 0);
}

// ---------------------------------------------------------------- diagnostic
__global__ void ws_diag_kernel(float* out, int n, float val) {
  int i = blockIdx.x * 256 + threadIdx.x;
  if (i < n) out[i] = val;
}

// ---------------------------------------------------------------- convert x
__global__ __launch_bounds__(256) void convert_x_kernel(
    const float* __restrict__ x, __hip_bfloat16* __restrict__ xc, int n8) {
  int i = blockIdx.x * 256 + threadIdx.x;
  if (i >= n8) return;
  float4 a = ((const float4*)x)[i * 2], b = ((const float4*)x)[i * 2 + 1];
  __hip_bfloat16 o[8] = {__float2bfloat16(a.x), __float2bfloat16(a.y),
                         __float2bfloat16(a.z), __float2bfloat16(a.w),
                         __float2bfloat16(b.x), __float2bfloat16(b.y),
                         __float2bfloat16(b.z), __float2bfloat16(b.w)};
  *(int4*)(xc + (size_t)i * 8) = *(const int4*)o;
}

// ---------------------------------------------------------------- cvt+transpose
__global__ void convert_transpose_kernel(const float* __restrict__ W,
                                         __hip_bfloat16* __restrict__ Wt,
                                         int rows, int cols) {
  __shared__ __hip_bfloat16 tile[32][33];
  const int tc = blockIdx.x * 32, tr = blockIdx.y * 32;
  const int tx = threadIdx.x, ty = threadIdx.y;  // block (32,8)
#pragma unroll
  for (int i = 0; i < 4; ++i) {
    int r = ty + i * 8;
    tile[r][tx] = __float2bfloat16(W[(size_t)(tr + r) * cols + tc + tx]);
  }
  __syncthreads();
#pragma unroll
  for (int i = 0; i < 4; ++i) {
    int r = ty + i * 8;
    Wt[(size_t)(tc + r) * rows + tr + tx] = tile[tx][r];
  }
}

// ---------------------------------------------------------------- GEMM common
constexpr int GK = 768;

// ---------------------------------------------------------------- QKV GEMM
// R11 structure: 128x128 tile, BK=32 (24 K-steps), 4 waves, 16KB LDS.
// Epilogue: Q/K row-major [96][1024][64]; V blocks (blockIdx.y>=12) write
// Vt [96][64][1024] via per-wave LDS bounce -> coalesced 16B stores.
__global__ __launch_bounds__(256) void gemm_qkv_kernel(
    const __hip_bfloat16* __restrict__ A,    // xc bf16 [8192][768]
    const __hip_bfloat16* __restrict__ Bt,   // WqkvT [2304][768] bf16
    const float* __restrict__ bias,          // b_qkv fp32 [2304]
    __hip_bfloat16* __restrict__ Qw,         // [96][1024][64] (Q scaled log2e/8)
    __hip_bfloat16* __restrict__ Kw,         // [96][1024][64]
    __hip_bfloat16* __restrict__ Vt) {       // [96][64][1024] TRANSPOSED
  __shared__ __align__(16) __bf16 smem[8192];  // As[0:4096) Bs[4096:8192)
  __bf16* As = smem;
  __bf16* Bs = smem + 4096;
  const int tid = threadIdx.x;
  const int lane = tid & 63, wave = tid >> 6;
  const int wr = wave >> 1, wc = wave & 1;
  const int m0 = blockIdx.x * 128, n0 = blockIdx.y * 128;
  const int fr = lane & 15, q4 = lane >> 4;

  const int r4 = lane >> 2, c8 = (lane & 3) * 8;
  const __hip_bfloat16* ga0 = A + (size_t)(m0 + wave * 32 + r4) * GK + c8;
  const __hip_bfloat16* gb0 = Bt + (size_t)(n0 + wave * 32 + r4) * GK + c8;
  __bf16* la0 = &As[wave * 1024];
  __bf16* lb0 = &Bs[wave * 1024];

  f32x4 acc[4][4] = {};

  for (int kt = 0; kt < GK / 32; ++kt) {
    __syncthreads();
    gload16(ga0 + kt * 32, la0);
    gload16(ga0 + kt * 32 + 16 * GK, la0 + 512);
    gload16(gb0 + kt * 32, lb0);
    gload16(gb0 + kt * 32 + 16 * GK, lb0 + 512);
    __syncthreads();
    bf16x8 af[4], bfr[4];
#pragma unroll
    for (int i = 0; i < 4; ++i)
      af[i] = *(const bf16x8*)(&As[(wr * 64 + i * 16 + fr) * 32 + q4 * 8]);
#pragma unroll
    for (int j = 0; j < 4; ++j)
      bfr[j] = *(const bf16x8*)(&Bs[(wc * 64 + j * 16 + fr) * 32 + q4 * 8]);
#pragma unroll
    for (int i = 0; i < 4; ++i)
#pragma unroll
      for (int j = 0; j < 4; ++j)
        acc[i][j] = MFMA16(af[i], bfr[j], acc[i][j]);
  }

  if (n0 < 1536) {
    // ---- Q/K epilogue (row-major scatter, as R11) ----
#pragma unroll
    for (int j = 0; j < 4; ++j) {
      int col = n0 + wc * 64 + j * 16 + fr;
      int which = (col >= 768) ? 1 : 0;  // 0=Q, 1=K (no V here)
      int rem = col - which * 768;
      int h = rem >> 6, d = rem & 63;
      float bv = bias[col];
      __hip_bfloat16* dst = (which == 0) ? Qw : Kw;
      // Q scale = 1/sqrt(64) * log2(e), so attention can use raw exp2.
      float scale = (which == 0) ? 0.18033688011112042f : 1.0f;
#pragma unroll
      for (int i = 0; i < 4; ++i) {
#pragma unroll
        for (int r = 0; r < 4; ++r) {
          int row = m0 + wr * 64 + i * 16 + q4 * 4 + r;
          int bb = row >> 10, nn = row & 1023;
          float v = (acc[i][j][r] + bv) * scale;
          dst[(((size_t)(bb * 12 + h) * 1024 + nn) << 6) + d] = __float2bfloat16(v);
        }
      }
    }
  } else {
    // ---- V epilogue: per-wave LDS transpose -> coalesced 128B segments ----
    // Wave tile: rows (n) m0+wr*64 .. +63, cols = one head, d = j*16+fr.
    __syncthreads();  // all waves done reading As/Bs fragments
    __bf16* sep = smem + wave * 2048;  // private [16 d][stride 72]
    const int page = ((m0 + wr * 64) >> 10) * 12 + ((n0 - 1536) >> 6) + wc;
    const int nn0 = (m0 + wr * 64) & 1023;
    __hip_bfloat16* vb = Vt + ((size_t)page << 16) + nn0;
#pragma unroll
    for (int j = 0; j < 4; ++j) {
      float bv = bias[n0 + wc * 64 + j * 16 + fr];
      // write phase: lane (fr,q4) holds n = i*16+q4*4+r at d_local = fr
#pragma unroll
      for (int i = 0; i < 4; ++i) {
        __hip_bfloat16 o[4];
#pragma unroll
        for (int r = 0; r < 4; ++r) o[r] = __float2bfloat16(acc[i][j][r] + bv);
        *(int2*)(&sep[fr * 72 + i * 16 + q4 * 4]) = *(const int2*)o;
      }
      // read phase (same wave, cross-lane; lgkmcnt orders vs writes above):
      // row d_local = it*8 + (lane>>3), 8 lanes x 16B = 128B contiguous/row
#pragma unroll
      for (int it = 0; it < 2; ++it) {
        int dl = it * 8 + (lane >> 3), k8 = (lane & 7) * 8;
        int4 vv = *(const int4*)(&sep[dl * 72 + k8]);
        *(int4*)(vb + ((size_t)(j * 16 + dl) << 10) + k8) = vv;
      }
    }
  }
}

// ---------------------------------------------------------------- proj GEMM
__global__ __launch_bounds__(256) void gemm_proj_kernel(
    const __hip_bfloat16* __restrict__ A,   // attnO bf16 [8192][768]
    const __hip_bfloat16* __restrict__ Bt,  // WprojT bf16 [768][768]
    const float* __restrict__ bias,         // b_proj fp32 [768]
    float* __restrict__ out) {              // d_out fp32 [8192][768]
  __shared__ __align__(16) __bf16 As[128 * 32];
  __shared__ __align__(16) __bf16 Bs[128 * 32];
  const int tid = threadIdx.x;
  const int lane = tid & 63, wave = tid >> 6;
  const int wr = wave >> 1, wc = wave & 1;
  const int m0 = blockIdx.x * 128, n0 = blockIdx.y * 128;
  const int fr = lane & 15, q4 = lane >> 4;

  const int r4 = lane >> 2, c8 = (lane & 3) * 8;
  const __hip_bfloat16* ga0 = A + (size_t)(m0 + wave * 32 + r4) * GK + c8;
  const __hip_bfloat16* gb0 = Bt + (size_t)(n0 + wave * 32 + r4) * GK + c8;
  __bf16* la0 = &As[wave * 1024];
  __bf16* lb0 = &Bs[wave * 1024];

  f32x4 acc[4][4] = {};

  for (int kt = 0; kt < GK / 32; ++kt) {
    __syncthreads();
    gload16(ga0 + kt * 32, la0);
    gload16(ga0 + kt * 32 + 16 * GK, la0 + 512);
    gload16(gb0 + kt * 32, lb0);
    gload16(gb0 + kt * 32 + 16 * GK, lb0 + 512);
    __syncthreads();
    bf16x8 af[4], bfr[4];
#pragma unroll
    for (int i = 0; i < 4; ++i)
      af[i] = *(const bf16x8*)(&As[(wr * 64 + i * 16 + fr) * 32 + q4 * 8]);
#pragma unroll
    for (int j = 0; j < 4; ++j)
      bfr[j] = *(const bf16x8*)(&Bs[(wc * 64 + j * 16 + fr) * 32 + q4 * 8]);
#pragma unroll
    for (int i = 0; i < 4; ++i)
#pragma unroll
      for (int j = 0; j < 4; ++j)
        acc[i][j] = MFMA16(af[i], bfr[j], acc[i][j]);
  }

#pragma unroll
  for (int j = 0; j < 4; ++j) {
    int col = n0 + wc * 64 + j * 16 + fr;
    float bv = bias[col];
#pragma unroll
    for (int i = 0; i < 4; ++i) {
#pragma unroll
      for (int r = 0; r < 4; ++r) {
        int row = m0 + wr * 64 + i * 16 + q4 * 4 + r;
        out[(size_t)row * 768 + col] = acc[i][j][r] + bv;
      }
    }
  }
}

// ---------------------------------------------------------------- attention
// block = (b,h,128 q-rows); 8 waves x 16 qrows; KV tiles of 64 keys.
// S^T = K.Q^T via operand swap; P stays in registers (sigma key permutation
// shared by P regs and V LDS layout). XCD swizzle bh=bx%96.
// K/V double-buffered; buf1 reuses the dead Q staging region. One barrier
// per KV tile; two prefetch register sets (T14); setprio around MFMA (T5).
__global__ __launch_bounds__(512) void attn_kernel(
    const __hip_bfloat16* __restrict__ Qw,  // [96][1024][64], scaled log2e/8
    const __hip_bfloat16* __restrict__ Kw,  // [96][1024][64]
    const __hip_bfloat16* __restrict__ Vt,  // [96][64][1024]
    __hip_bfloat16* __restrict__ O) {       // attnO [8192][768], col = h*64+d
  constexpr int LP = 72;
  // [0,9216): Q staging, then buf1 {K1@0, V1@4608}
  // [9216,18432): buf0 {K0@9216, V0@13824}
  __shared__ __bf16 smem[18432];
  __bf16* Qs = smem;
  __bf16* K1 = smem;
  __bf16* V1 = smem + 4608;
  __bf16* K0 = smem + 9216;
  __bf16* V0 = smem + 13824;
  const int tid = threadIdx.x;
  const int lane = tid & 63, wave = tid >> 6;  // 8 waves
  const int fr = lane & 15, q4 = lane >> 4;
  const int bh = blockIdx.x % 96, qt = blockIdx.x / 96;  // XCD-local KV
  const __hip_bfloat16* Qb = Qw + ((size_t)bh * 1024 + qt * 128) * 64;
  const __hip_bfloat16* Kb = Kw + (size_t)bh * 65536;
  const __hip_bfloat16* Vb = Vt + (size_t)bh * 65536;

  // deep prefetch: tile 0 into reg set A
  const int krow = tid >> 3, kc = (tid & 7) * 8;
  int4 kregA = *(const int4*)(Kb + (size_t)krow * 64 + kc);
  int4 vregA = *(const int4*)(Vb + ((size_t)krow << 10) + kc);

  // stage Q 128x64 (2 int4/thread)
#pragma unroll
  for (int i = 0; i < 2; ++i) {
    int s = tid + 512 * i;
    int row = s >> 3, c = (s & 7) * 8;
    *(int4*)(&Qs[row * LP + c]) = *(const int4*)(Qb + row * 64 + c);
  }
  __syncthreads();
  bf16x8 qf[2];
#pragma unroll
  for (int ks = 0; ks < 2; ++ks)
    qf[ks] = *(const bf16x8*)(&Qs[(wave * 16 + fr) * LP + ks * 32 + q4 * 8]);

  float l_i = 0.f;        // per-lane partial over this lane's 16 keys/iter
  f32x4 accO[4] = {};     // C-layout: row=qrow(q4*4+r), col=d(dt*16+fr)

  // sigma destination base for V staging (lane-constant)
  const int sc8 = tid & 7;  // which 8-key chunk this thread stages
  const int sbase = ((sc8 >> 2) << 5) | ((sc8 & 1) << 4) | (((sc8 >> 1) & 1) << 2);

  // prolog: write buf0 <- tile 0; prefetch tile 1 into reg set B
  *(int4*)(&K0[krow * LP + kc]) = kregA;
  *(int2*)(&V0[krow * LP + sbase]) = make_int2(vregA.x, vregA.y);
  *(int2*)(&V0[krow * LP + sbase + 8]) = make_int2(vregA.z, vregA.w);
  int4 kregB = *(const int4*)(Kb + (size_t)(64 + krow) * 64 + kc);
  int4 vregB = *(const int4*)(Vb + ((size_t)krow << 10) + 64 + kc);
  __syncthreads();  // buf0 ready; all qf reads done -> Q region free

  auto compute_tile = [&](const __bf16* Kbuf, const __bf16* Vbuf) {
    // S^T = K.Q^T: scT[nt][r] = P[qrow=wave*16+fr][key=nt*16+q4*4+r]
    f32x4 scT[4];
    __builtin_amdgcn_s_setprio(1);
#pragma unroll
    for (int nt = 0; nt < 4; ++nt) {
      bf16x8 kf0 = *(const bf16x8*)(&Kbuf[(nt * 16 + fr) * LP + q4 * 8]);
      bf16x8 kf1 = *(const bf16x8*)(&Kbuf[(nt * 16 + fr) * LP + 32 + q4 * 8]);
      f32x4 z = {};
      z = MFMA16(kf0, qf[0], z);
      scT[nt] = MFMA16(kf1, qf[1], z);
    }
    __builtin_amdgcn_s_setprio(0);
    // p = 2^s (bare v_exp_f32); per-lane l partial
    float rs = 0.f;
#pragma unroll
    for (int nt = 0; nt < 4; ++nt)
#pragma unroll
      for (int r = 0; r < 4; ++r) {
        float p = EXP2(scT[nt][r]);
        scT[nt][r] = p;
        rs += p;
      }
    l_i += rs;
    // O += P.V — P A-fragments are this lane's own registers under sigma
#pragma unroll
    for (int ks = 0; ks < 2; ++ks) {
      bf16x8 pf;
#pragma unroll
      for (int e = 0; e < 4; ++e) {
        pf[e] = to_bf16(scT[2 * ks][e]);
        pf[4 + e] = to_bf16(scT[2 * ks + 1][e]);
      }
      __builtin_amdgcn_s_setprio(1);
#pragma unroll
      for (int dt = 0; dt < 4; ++dt) {
        bf16x8 vf = *(const bf16x8*)(&Vbuf[(dt * 16 + fr) * LP + ks * 32 + q4 * 8]);
        accO[dt] = MFMA16(pf, vf, accO[dt]);
      }
      __builtin_amdgcn_s_setprio(0);
    }
  };

  for (int kt2 = 0; kt2 < 16; kt2 += 2) {
    // even phase: compute tile kt2 from buf0; stage kt2+1 -> buf1;
    // prefetch kt2+2 -> reg set A
    compute_tile(K0, V0);
    *(int4*)(&K1[krow * LP + kc]) = kregB;
    *(int2*)(&V1[krow * LP + sbase]) = make_int2(vregB.x, vregB.y);
    *(int2*)(&V1[krow * LP + sbase + 8]) = make_int2(vregB.z, vregB.w);
    if (kt2 + 2 < 16) {
      kregA = *(const int4*)(Kb + (size_t)((kt2 + 2) * 64 + krow) * 64 + kc);
      vregA = *(const int4*)(Vb + ((size_t)krow << 10) + (kt2 + 2) * 64 + kc);
    }
    __syncthreads();
    // odd phase: compute tile kt2+1 from buf1; stage kt2+2 -> buf0;
    // prefetch kt2+3 -> reg set B
    compute_tile(K1, V1);
    if (kt2 + 2 < 16) {
      *(int4*)(&K0[krow * LP + kc]) = kregA;
      *(int2*)(&V0[krow * LP + sbase]) = make_int2(vregA.x, vregA.y);
      *(int2*)(&V0[krow * LP + sbase + 8]) = make_int2(vregA.z, vregA.w);
      kregB = *(const int4*)(Kb + (size_t)((kt2 + 3) * 64 + krow) * 64 + kc);
      vregB = *(const int4*)(Vb + ((size_t)krow << 10) + (kt2 + 3) * 64 + kc);
      __syncthreads();
    }
  }

  // l: reduce across the 4 quads -> full sum per fr; then broadcast to rows.
  l_i += __shfl_xor(l_i, 16, 64);
  l_i += __shfl_xor(l_i, 32, 64);
  float lrow[4];
#pragma unroll
  for (int r = 0; r < 4; ++r) lrow[r] = __shfl(l_i, q4 * 4 + r, 64);

  const int h = bh % 12, bb = bh / 12;
#pragma unroll
  for (int dt = 0; dt < 4; ++dt)
#pragma unroll
    for (int r = 0; r < 4; ++r) {
      int row = bb * 1024 + qt * 128 + wave * 16 + q4 * 4 + r;
      int col = h * 64 + dt * 16 + fr;
      O[(size_t)row * 768 + col] = __float2bfloat16(accO[dt][r] / lrow[r]);
    }
}

// ---------------------------------------------------------------- launch
extern "C" void kernel_launch(void* const* d_in, const int* in_sizes, int n_in,
                              void* d_out, int out_size, void* d_ws, size_t ws_size,
                              hipStream_t stream) {
  const float* x     = (const float*)d_in[0];  // [8192][768]
  const float* Wqkv  = (const float*)d_in[1];  // [768][2304]
  const float* bqkv  = (const float*)d_in[2];  // [2304]
  const float* Wproj = (const float*)d_in[3];  // [768][768]
  const float* bproj = (const float*)d_in[4];  // [768]
  float* out = (float*)d_out;                  // [8192][768] fp32

  constexpr size_t NEEDED = 55050240;
  if (ws_size < NEEDED) {
    ws_diag_kernel<<<(out_size + 255) / 256, 256, 0, stream>>>(
        out, out_size, (float)(ws_size >> 20));
    return;
  }

  char* ws = (char*)d_ws;
  __hip_bfloat16* WqkvT  = (__hip_bfloat16*)(ws);               // 3,538,944 B
  __hip_bfloat16* WprojT = (__hip_bfloat16*)(ws + 3538944);     // 1,179,648 B
  __hip_bfloat16* Qw     = (__hip_bfloat16*)(ws + 4718592);     // 12,582,912 B
  __hip_bfloat16* Kw     = (__hip_bfloat16*)(ws + 17301504);    // 12,582,912 B
  __hip_bfloat16* Vt     = (__hip_bfloat16*)(ws + 29884416);    // 12,582,912 B (transposed V, written by gemm_qkv)
  __hip_bfloat16* xc     = (__hip_bfloat16*)(ws + 42467328);    // 12,582,912 B
  __hip_bfloat16* attnO  = xc;  // xc dead after gemm_qkv
  // end = 55,050,240 (proven available)

  convert_x_kernel<<<3072, 256, 0, stream>>>(x, xc, 786432);
  convert_transpose_kernel<<<dim3(72, 24), dim3(32, 8), 0, stream>>>(
      Wqkv, WqkvT, 768, 2304);
  convert_transpose_kernel<<<dim3(24, 24), dim3(32, 8), 0, stream>>>(
      Wproj, WprojT, 768, 768);
  gemm_qkv_kernel<<<dim3(64, 18), 256, 0, stream>>>(xc, WqkvT, bqkv, Qw, Kw, Vt);
  attn_kernel<<<dim3(96 * 8), 512, 0, stream>>>(Qw, Kw, Vt, attnO);
  gemm_proj_kernel<<<dim3(64, 6), 256, 0, stream>>>(attnO, WprojT, bproj, out);
}

// Round 6
// 191.048 us; speedup vs baseline: 1.0351x; 1.0351x over previous
//
#include <hip/hip_runtime.h>
#include <hip/hip_bf16.h>

// MHA forward. Inputs fp32, output fp32, compute bf16 MFMA w/ fp32 accum.
// B=8, N=1024, DIM=768, NH=12, HD=64, M=8192.
// R17: revert qkv to R11-exact (VGPR 80 / 16KB LDS / row-major V) + separate
// vtrans. Evidence R12-R16: any qkv change crossing VGPR~80 or 16KB LDS
// loses ~20% to occupancy (R13 swizzle +16 VGPR; R16 bounce epilogue +16
// VGPR -> 5 waves/SIMD). V-path options measured: R11 split 48.2+6 us <
// R14 fused-scatter 55.0 < R16 fused-bounce 58.4.
// NEW: prep work (x->bf16 convert + both W transposes) merged into ONE
// kernel via block-range dispatch (launch count 5->4).
// R14 carried (attn): double-buffered K/V reusing dead Q LDS region, 1
// barrier/KV-tile, 2 prefetch reg sets (T14), setprio around MFMA (T5).
// R11 carried: GEMM BK=32 128^2 2-phase, 512-thread attn, bare v_exp_f32,
// S^T operand swap + sigma permutation, XCD swizzle bh=bx%96, deferred
// l-reduction, V pre-transposed for attn.
// WS high-water 55,050,240 B (proven available).

typedef __bf16 bf16x8 __attribute__((ext_vector_type(8)));
typedef float f32x4 __attribute__((ext_vector_type(4)));

#define MFMA16(a, b, c) __builtin_amdgcn_mfma_f32_16x16x32_bf16(a, b, c, 0, 0, 0)

#if defined(__has_builtin) && __has_builtin(__builtin_amdgcn_exp2f)
#define EXP2(x) __builtin_amdgcn_exp2f(x)
#else
#define EXP2(x) exp2f(x)
#endif

__device__ inline __bf16 to_bf16(float f) {
  __hip_bfloat16 h = __float2bfloat16(f);
  return *reinterpret_cast<__bf16*>(&h);
}

// Direct global->LDS DMA, 16B per lane. LDS dest is wave-uniform base + lane*16.
__device__ __forceinline__ void gload16(const void* g, void* l) {
  __builtin_amdgcn_global_load_lds(
      (const __attribute__((address_space(1))) unsigned int*)(unsigned long long)g,
      (__attribute__((address_space(3))) unsigned int*)(unsigned long long)l,
      16, 0, 0);
}

// ---------------------------------------------------------------- diagnostic
__global__ void ws_diag_kernel(float* out, int n, float val) {
  int i = blockIdx.x * 256 + threadIdx.x;
  if (i < n) out[i] = val;
}

// ---------------------------------------------------------------- fused prep
// blocks [0,3072): x fp32 -> xc bf16 (8 elems/thread)
// blocks [3072,4800): Wqkv [768][2304] -> WqkvT [2304][768] bf16 (72x24 tiles)
// blocks [4800,5376): Wproj [768][768] -> WprojT [768][768] bf16 (24x24 tiles)
__global__ __launch_bounds__(256) void prep_kernel(
    const float* __restrict__ x, __hip_bfloat16* __restrict__ xc,
    const float* __restrict__ Wqkv, __hip_bfloat16* __restrict__ WqkvT,
    const float* __restrict__ Wproj, __hip_bfloat16* __restrict__ WprojT) {
  __shared__ __hip_bfloat16 tile[32][33];
  const int b = blockIdx.x;
  if (b < 3072) {
    int i = b * 256 + threadIdx.x;
    float4 a = ((const float4*)x)[i * 2], c = ((const float4*)x)[i * 2 + 1];
    __hip_bfloat16 o[8] = {__float2bfloat16(a.x), __float2bfloat16(a.y),
                           __float2bfloat16(a.z), __float2bfloat16(a.w),
                           __float2bfloat16(c.x), __float2bfloat16(c.y),
                           __float2bfloat16(c.z), __float2bfloat16(c.w)};
    *(int4*)(xc + (size_t)i * 8) = *(const int4*)o;
    return;
  }
  const float* W;
  __hip_bfloat16* Wt;
  int rows, cols, bx, by;
  if (b < 4800) {
    int idx = b - 3072;  // 72 x 24 tile grid
    W = Wqkv; Wt = WqkvT; rows = 768; cols = 2304;
    bx = idx % 72; by = idx / 72;
  } else {
    int idx = b - 4800;  // 24 x 24 tile grid
    W = Wproj; Wt = WprojT; rows = 768; cols = 768;
    bx = idx % 24; by = idx / 24;
  }
  const int tc = bx * 32, tr = by * 32;
  const int tx = threadIdx.x & 31, ty = threadIdx.x >> 5;  // (32,8)
#pragma unroll
  for (int i = 0; i < 4; ++i) {
    int r = ty + i * 8;
    tile[r][tx] = __float2bfloat16(W[(size_t)(tr + r) * cols + tc + tx]);
  }
  __syncthreads();
#pragma unroll
  for (int i = 0; i < 4; ++i) {
    int r = ty + i * 8;
    Wt[(size_t)(tc + r) * rows + tr + tx] = tile[tx][r];
  }
}

// ---------------------------------------------------------------- V transpose
// Vrow [96][1024][64] -> Vt [96][64][1024]. 64x64 bf16 tile per block.
__global__ __launch_bounds__(256) void vtrans_kernel(
    const __hip_bfloat16* __restrict__ Vrow, __hip_bfloat16* __restrict__ Vt) {
  constexpr int LP = 72;
  __shared__ __bf16 tile[64 * LP];
  const int tid = threadIdx.x;
  const int bh = blockIdx.x;
  const int n0 = blockIdx.y * 64;
  const size_t base = (size_t)bh << 16;
#pragma unroll
  for (int i = 0; i < 2; ++i) {
    int s = tid + 256 * i;
    int r = s >> 3, c8 = (s & 7) * 8;
    *(int4*)(&tile[r * LP + c8]) =
        *(const int4*)(Vrow + base + (size_t)(n0 + r) * 64 + c8);
  }
  __syncthreads();
#pragma unroll
  for (int i = 0; i < 2; ++i) {
    int s = tid + 256 * i;
    int d = s >> 3, n8 = (s & 7) * 8;
    __bf16 o[8];
#pragma unroll
    for (int j = 0; j < 8; ++j) o[j] = tile[(n8 + j) * LP + d];
    *(int4*)(Vt + base + ((size_t)d << 10) + n0 + n8) = *(const int4*)o;
  }
}

// ---------------------------------------------------------------- GEMM common
constexpr int GK = 768;

// ---------------------------------------------------------------- QKV GEMM
// R11-exact: 128x128 tile, BK=32 (24 K-steps), 4 waves, 16KB LDS, VGPR 80.
__global__ __launch_bounds__(256) void gemm_qkv_kernel(
    const __hip_bfloat16* __restrict__ A,    // xc bf16 [8192][768]
    const __hip_bfloat16* __restrict__ Bt,   // WqkvT [2304][768] bf16
    const float* __restrict__ bias,          // b_qkv fp32 [2304]
    __hip_bfloat16* __restrict__ Qw,         // [96][1024][64] (Q scaled log2e/8)
    __hip_bfloat16* __restrict__ Kw,         // [96][1024][64]
    __hip_bfloat16* __restrict__ Vw) {       // [96][1024][64] row-major
  __shared__ __align__(16) __bf16 As[128 * 32];
  __shared__ __align__(16) __bf16 Bs[128 * 32];
  const int tid = threadIdx.x;
  const int lane = tid & 63, wave = tid >> 6;
  const int wr = wave >> 1, wc = wave & 1;
  const int m0 = blockIdx.x * 128, n0 = blockIdx.y * 128;
  const int fr = lane & 15, q4 = lane >> 4;

  const int r4 = lane >> 2, c8 = (lane & 3) * 8;
  const __hip_bfloat16* ga0 = A + (size_t)(m0 + wave * 32 + r4) * GK + c8;
  const __hip_bfloat16* gb0 = Bt + (size_t)(n0 + wave * 32 + r4) * GK + c8;
  __bf16* la0 = &As[wave * 1024];
  __bf16* lb0 = &Bs[wave * 1024];

  f32x4 acc[4][4] = {};

  for (int kt = 0; kt < GK / 32; ++kt) {
    __syncthreads();
    gload16(ga0 + kt * 32, la0);
    gload16(ga0 + kt * 32 + 16 * GK, la0 + 512);
    gload16(gb0 + kt * 32, lb0);
    gload16(gb0 + kt * 32 + 16 * GK, lb0 + 512);
    __syncthreads();
    bf16x8 af[4], bfr[4];
#pragma unroll
    for (int i = 0; i < 4; ++i)
      af[i] = *(const bf16x8*)(&As[(wr * 64 + i * 16 + fr) * 32 + q4 * 8]);
#pragma unroll
    for (int j = 0; j < 4; ++j)
      bfr[j] = *(const bf16x8*)(&Bs[(wc * 64 + j * 16 + fr) * 32 + q4 * 8]);
#pragma unroll
    for (int i = 0; i < 4; ++i)
#pragma unroll
      for (int j = 0; j < 4; ++j)
        acc[i][j] = MFMA16(af[i], bfr[j], acc[i][j]);
  }

#pragma unroll
  for (int j = 0; j < 4; ++j) {
    int col = n0 + wc * 64 + j * 16 + fr;
    int which = col / 768;
    int rem = col - which * 768;
    int h = rem >> 6, d = rem & 63;
    float bv = bias[col];
    __hip_bfloat16* dst = (which == 0) ? Qw : (which == 1) ? Kw : Vw;
    // Q scale = 1/sqrt(64) * log2(e), so attention can use raw exp2.
    float scale = (which == 0) ? 0.18033688011112042f : 1.0f;
#pragma unroll
    for (int i = 0; i < 4; ++i) {
#pragma unroll
      for (int r = 0; r < 4; ++r) {
        int row = m0 + wr * 64 + i * 16 + q4 * 4 + r;
        int bb = row >> 10, nn = row & 1023;
        float v = (acc[i][j][r] + bv) * scale;
        dst[(((size_t)(bb * 12 + h) * 1024 + nn) << 6) + d] = __float2bfloat16(v);
      }
    }
  }
}

// ---------------------------------------------------------------- proj GEMM
__global__ __launch_bounds__(256) void gemm_proj_kernel(
    const __hip_bfloat16* __restrict__ A,   // attnO bf16 [8192][768]
    const __hip_bfloat16* __restrict__ Bt,  // WprojT bf16 [768][768]
    const float* __restrict__ bias,         // b_proj fp32 [768]
    float* __restrict__ out) {              // d_out fp32 [8192][768]
  __shared__ __align__(16) __bf16 As[128 * 32];
  __shared__ __align__(16) __bf16 Bs[128 * 32];
  const int tid = threadIdx.x;
  const int lane = tid & 63, wave = tid >> 6;
  const int wr = wave >> 1, wc = wave & 1;
  const int m0 = blockIdx.x * 128, n0 = blockIdx.y * 128;
  const int fr = lane & 15, q4 = lane >> 4;

  const int r4 = lane >> 2, c8 = (lane & 3) * 8;
  const __hip_bfloat16* ga0 = A + (size_t)(m0 + wave * 32 + r4) * GK + c8;
  const __hip_bfloat16* gb0 = Bt + (size_t)(n0 + wave * 32 + r4) * GK + c8;
  __bf16* la0 = &As[wave * 1024];
  __bf16* lb0 = &Bs[wave * 1024];

  f32x4 acc[4][4] = {};

  for (int kt = 0; kt < GK / 32; ++kt) {
    __syncthreads();
    gload16(ga0 + kt * 32, la0);
    gload16(ga0 + kt * 32 + 16 * GK, la0 + 512);
    gload16(gb0 + kt * 32, lb0);
    gload16(gb0 + kt * 32 + 16 * GK, lb0 + 512);
    __syncthreads();
    bf16x8 af[4], bfr[4];
#pragma unroll
    for (int i = 0; i < 4; ++i)
      af[i] = *(const bf16x8*)(&As[(wr * 64 + i * 16 + fr) * 32 + q4 * 8]);
#pragma unroll
    for (int j = 0; j < 4; ++j)
      bfr[j] = *(const bf16x8*)(&Bs[(wc * 64 + j * 16 + fr) * 32 + q4 * 8]);
#pragma unroll
    for (int i = 0; i < 4; ++i)
#pragma unroll
      for (int j = 0; j < 4; ++j)
        acc[i][j] = MFMA16(af[i], bfr[j], acc[i][j]);
  }

#pragma unroll
  for (int j = 0; j < 4; ++j) {
    int col = n0 + wc * 64 + j * 16 + fr;
    float bv = bias[col];
#pragma unroll
    for (int i = 0; i < 4; ++i) {
#pragma unroll
      for (int r = 0; r < 4; ++r) {
        int row = m0 + wr * 64 + i * 16 + q4 * 4 + r;
        out[(size_t)row * 768 + col] = acc[i][j][r] + bv;
      }
    }
  }
}

// ---------------------------------------------------------------- attention
// block = (b,h,128 q-rows); 8 waves x 16 qrows; KV tiles of 64 keys.
// S^T = K.Q^T via operand swap; P stays in registers (sigma key permutation
// shared by P regs and V LDS layout). XCD swizzle bh=bx%96.
// K/V double-buffered; buf1 reuses the dead Q staging region. One barrier
// per KV tile; two prefetch register sets (T14); setprio around MFMA (T5).
__global__ __launch_bounds__(512) void attn_kernel(
    const __hip_bfloat16* __restrict__ Qw,  // [96][1024][64], scaled log2e/8
    const __hip_bfloat16* __restrict__ Kw,  // [96][1024][64]
    const __hip_bfloat16* __restrict__ Vt,  // [96][64][1024]
    __hip_bfloat16* __restrict__ O) {       // attnO [8192][768], col = h*64+d
  constexpr int LP = 72;
  // [0,9216): Q staging, then buf1 {K1@0, V1@4608}
  // [9216,18432): buf0 {K0@9216, V0@13824}
  __shared__ __bf16 smem[18432];
  __bf16* Qs = smem;
  __bf16* K1 = smem;
  __bf16* V1 = smem + 4608;
  __bf16* K0 = smem + 9216;
  __bf16* V0 = smem + 13824;
  const int tid = threadIdx.x;
  const int lane = tid & 63, wave = tid >> 6;  // 8 waves
  const int fr = lane & 15, q4 = lane >> 4;
  const int bh = blockIdx.x % 96, qt = blockIdx.x / 96;  // XCD-local KV
  const __hip_bfloat16* Qb = Qw + ((size_t)bh * 1024 + qt * 128) * 64;
  const __hip_bfloat16* Kb = Kw + (size_t)bh * 65536;
  const __hip_bfloat16* Vb = Vt + (size_t)bh * 65536;

  // deep prefetch: tile 0 into reg set A
  const int krow = tid >> 3, kc = (tid & 7) * 8;
  int4 kregA = *(const int4*)(Kb + (size_t)krow * 64 + kc);
  int4 vregA = *(const int4*)(Vb + ((size_t)krow << 10) + kc);

  // stage Q 128x64 (2 int4/thread)
#pragma unroll
  for (int i = 0; i < 2; ++i) {
    int s = tid + 512 * i;
    int row = s >> 3, c = (s & 7) * 8;
    *(int4*)(&Qs[row * LP + c]) = *(const int4*)(Qb + row * 64 + c);
  }
  __syncthreads();
  bf16x8 qf[2];
#pragma unroll
  for (int ks = 0; ks < 2; ++ks)
    qf[ks] = *(const bf16x8*)(&Qs[(wave * 16 + fr) * LP + ks * 32 + q4 * 8]);

  float l_i = 0.f;        // per-lane partial over this lane's 16 keys/iter
  f32x4 accO[4] = {};     // C-layout: row=qrow(q4*4+r), col=d(dt*16+fr)

  // sigma destination base for V staging (lane-constant)
  const int sc8 = tid & 7;  // which 8-key chunk this thread stages
  const int sbase = ((sc8 >> 2) << 5) | ((sc8 & 1) << 4) | (((sc8 >> 1) & 1) << 2);

  // prolog: write buf0 <- tile 0; prefetch tile 1 into reg set B
  *(int4*)(&K0[krow * LP + kc]) = kregA;
  *(int2*)(&V0[krow * LP + sbase]) = make_int2(vregA.x, vregA.y);
  *(int2*)(&V0[krow * LP + sbase + 8]) = make_int2(vregA.z, vregA.w);
  int4 kregB = *(const int4*)(Kb + (size_t)(64 + krow) * 64 + kc);
  int4 vregB = *(const int4*)(Vb + ((size_t)krow << 10) + 64 + kc);
  __syncthreads();  // buf0 ready; all qf reads done -> Q region free

  auto compute_tile = [&](const __bf16* Kbuf, const __bf16* Vbuf) {
    // S^T = K.Q^T: scT[nt][r] = P[qrow=wave*16+fr][key=nt*16+q4*4+r]
    f32x4 scT[4];
    __builtin_amdgcn_s_setprio(1);
#pragma unroll
    for (int nt = 0; nt < 4; ++nt) {
      bf16x8 kf0 = *(const bf16x8*)(&Kbuf[(nt * 16 + fr) * LP + q4 * 8]);
      bf16x8 kf1 = *(const bf16x8*)(&Kbuf[(nt * 16 + fr) * LP + 32 + q4 * 8]);
      f32x4 z = {};
      z = MFMA16(kf0, qf[0], z);
      scT[nt] = MFMA16(kf1, qf[1], z);
    }
    __builtin_amdgcn_s_setprio(0);
    // p = 2^s (bare v_exp_f32); per-lane l partial
    float rs = 0.f;
#pragma unroll
    for (int nt = 0; nt < 4; ++nt)
#pragma unroll
      for (int r = 0; r < 4; ++r) {
        float p = EXP2(scT[nt][r]);
        scT[nt][r] = p;
        rs += p;
      }
    l_i += rs;
    // O += P.V — P A-fragments are this lane's own registers under sigma
#pragma unroll
    for (int ks = 0; ks < 2; ++ks) {
      bf16x8 pf;
#pragma unroll
      for (int e = 0; e < 4; ++e) {
        pf[e] = to_bf16(scT[2 * ks][e]);
        pf[4 + e] = to_bf16(scT[2 * ks + 1][e]);
      }
      __builtin_amdgcn_s_setprio(1);
#pragma unroll
      for (int dt = 0; dt < 4; ++dt) {
        bf16x8 vf = *(const bf16x8*)(&Vbuf[(dt * 16 + fr) * LP + ks * 32 + q4 * 8]);
        accO[dt] = MFMA16(pf, vf, accO[dt]);
      }
      __builtin_amdgcn_s_setprio(0);
    }
  };

  for (int kt2 = 0; kt2 < 16; kt2 += 2) {
    // even phase: compute tile kt2 from buf0; stage kt2+1 -> buf1;
    // prefetch kt2+2 -> reg set A
    compute_tile(K0, V0);
    *(int4*)(&K1[krow * LP + kc]) = kregB;
    *(int2*)(&V1[krow * LP + sbase]) = make_int2(vregB.x, vregB.y);
    *(int2*)(&V1[krow * LP + sbase + 8]) = make_int2(vregB.z, vregB.w);
    if (kt2 + 2 < 16) {
      kregA = *(const int4*)(Kb + (size_t)((kt2 + 2) * 64 + krow) * 64 + kc);
      vregA = *(const int4*)(Vb + ((size_t)krow << 10) + (kt2 + 2) * 64 + kc);
    }
    __syncthreads();
    // odd phase: compute tile kt2+1 from buf1; stage kt2+2 -> buf0;
    // prefetch kt2+3 -> reg set B
    compute_tile(K1, V1);
    if (kt2 + 2 < 16) {
      *(int4*)(&K0[krow * LP + kc]) = kregA;
      *(int2*)(&V0[krow * LP + sbase]) = make_int2(vregA.x, vregA.y);
      *(int2*)(&V0[krow * LP + sbase + 8]) = make_int2(vregA.z, vregA.w);
      kregB = *(const int4*)(Kb + (size_t)((kt2 + 3) * 64 + krow) * 64 + kc);
      vregB = *(const int4*)(Vb + ((size_t)krow << 10) + (kt2 + 3) * 64 + kc);
      __syncthreads();
    }
  }

  // l: reduce across the 4 quads -> full sum per fr; then broadcast to rows.
  l_i += __shfl_xor(l_i, 16, 64);
  l_i += __shfl_xor(l_i, 32, 64);
  float lrow[4];
#pragma unroll
  for (int r = 0; r < 4; ++r) lrow[r] = __shfl(l_i, q4 * 4 + r, 64);

  const int h = bh % 12, bb = bh / 12;
#pragma unroll
  for (int dt = 0; dt < 4; ++dt)
#pragma unroll
    for (int r = 0; r < 4; ++r) {
      int row = bb * 1024 + qt * 128 + wave * 16 + q4 * 4 + r;
      int col = h * 64 + dt * 16 + fr;
      O[(size_t)row * 768 + col] = __float2bfloat16(accO[dt][r] / lrow[r]);
    }
}

// ---------------------------------------------------------------- launch
extern "C" void kernel_launch(void* const* d_in, const int* in_sizes, int n_in,
                              void* d_out, int out_size, void* d_ws, size_t ws_size,
                              hipStream_t stream) {
  const float* x     = (const float*)d_in[0];  // [8192][768]
  const float* Wqkv  = (const float*)d_in[1];  // [768][2304]
  const float* bqkv  = (const float*)d_in[2];  // [2304]
  const float* Wproj = (const float*)d_in[3];  // [768][768]
  const float* bproj = (const float*)d_in[4];  // [768]
  float* out = (float*)d_out;                  // [8192][768] fp32

  constexpr size_t NEEDED = 55050240;
  if (ws_size < NEEDED) {
    ws_diag_kernel<<<(out_size + 255) / 256, 256, 0, stream>>>(
        out, out_size, (float)(ws_size >> 20));
    return;
  }

  char* ws = (char*)d_ws;
  __hip_bfloat16* WqkvT  = (__hip_bfloat16*)(ws);               // 3,538,944 B
  __hip_bfloat16* WprojT = (__hip_bfloat16*)(ws + 3538944);     // 1,179,648 B
  __hip_bfloat16* Qw     = (__hip_bfloat16*)(ws + 4718592);     // 12,582,912 B
  __hip_bfloat16* Kw     = (__hip_bfloat16*)(ws + 17301504);    // 12,582,912 B
  __hip_bfloat16* Vrow   = (__hip_bfloat16*)(ws + 29884416);    // 12,582,912 B
  __hip_bfloat16* xc     = (__hip_bfloat16*)(ws + 42467328);    // 12,582,912 B
  __hip_bfloat16* Vt     = xc;    // xc dead after gemm_qkv
  __hip_bfloat16* attnO  = Vrow;  // Vrow dead after vtrans
  // end = 55,050,240 (proven available)

  prep_kernel<<<5376, 256, 0, stream>>>(x, xc, Wqkv, WqkvT, Wproj, WprojT);
  gemm_qkv_kernel<<<dim3(64, 18), 256, 0, stream>>>(xc, WqkvT, bqkv, Qw, Kw, Vrow);
  vtrans_kernel<<<dim3(96, 16), 256, 0, stream>>>(Vrow, Vt);
  attn_kernel<<<dim3(96 * 8), 512, 0, stream>>>(Qw, Kw, Vt, attnO);
  gemm_proj_kernel<<<dim3(64, 6), 256, 0, stream>>>(attnO, WprojT, bproj, out);
}